// Round 12
// baseline (114.714 us; speedup 1.0000x reference)
//
#include <hip/hip_runtime.h>
#include <stdint.h>

#define DM_ 256
#define H_ 4
#define M_ 4096
#define KN_ 16
#define B_ 2
#define MK_ (M_*KN_)

typedef __attribute__((ext_vector_type(8))) short short8;
typedef __attribute__((ext_vector_type(4))) float f32x4;
typedef __attribute__((ext_vector_type(4))) unsigned short u16x4;

static __device__ __forceinline__ unsigned short f2bf(float x) {
  union { float f; uint32_t u; } v; v.f = x;
  uint32_t u = v.u + (0x7FFFu + ((v.u >> 16) & 1u));  // RNE
  return (unsigned short)(u >> 16);
}
static __device__ __forceinline__ float u2f(uint32_t u) {
  union { uint32_t u; float f; } v; v.u = u; return v.f;
}

// XOR swizzle for [col][k] bf16 tiles (row stride 512 B), bank-floor b128 reads/writes.
static __device__ __forceinline__ int swz512(int col, int kbyte) {
  int f = ((col >> 2) & 7) ^ ((col & 1) << 2);
  return (col << 9) + (kbyte ^ (f << 4));
}

// ---- prep2: weight products, fragment-linear bf16, fused biases ------------------------
__global__ void prep2(const float* __restrict__ Wq, const float* __restrict__ bq,
                      const float* __restrict__ Wk, const float* __restrict__ Wv,
                      const float* __restrict__ bv, const float* __restrict__ Wm,
                      const float* __restrict__ bm,
                      unsigned short* __restrict__ W2T, unsigned short* __restrict__ Wmv,
                      float* __restrict__ qb2, float* __restrict__ btot) {
  int t = blockIdx.x * 512 + threadIdx.x;
  if (t < 262144) {                       // W2T fragment-linear [kstep8][rowblk64][lane][8]
    int j = t & 7, lane = (t >> 3) & 63, rowblk = (t >> 9) & 63, kstep = t >> 15;
    int row = rowblk * 16 + (lane & 15);
    int k = kstep * 32 + (lane >> 4) * 8 + j;
    int h = row >> 8, c = row & 255;
    float v = 0.f;
#pragma unroll 8
    for (int d = 0; d < 64; ++d) v += Wq[(4 * d + h) * 256 + k] * Wk[(4 * d + h) * 256 + c];
    W2T[t] = f2bf(v);
  } else if (t < 524288) {                // Wmv fragment-linear [kstep32][rowblk16][lane][8]
    int e = t - 262144;
    int j = e & 7, lane = (e >> 3) & 63, rowblk = (e >> 9) & 15, kstep = e >> 13;
    int o = rowblk * 16 + (lane & 15);
    int kidx = kstep * 32 + (lane >> 4) * 8 + j;
    int c = kidx >> 2, h = kidx & 3;
    float v = 0.f;
#pragma unroll 8
    for (int d = 0; d < 64; ++d) v += Wm[o * 256 + 4 * d + h] * Wv[(4 * d + h) * 256 + c];
    Wmv[e] = f2bf(v);
  } else if (t < 525312) {
    int r = t - 524288; int h = r >> 8, c = r & 255;
    float v = 0.f;
#pragma unroll 8
    for (int d = 0; d < 64; ++d) v += bq[4 * d + h] * Wk[(4 * d + h) * 256 + c];
    qb2[r] = v;
  } else if (t < 525568) {
    int o = t - 525312;
    float v = bm[o];
#pragma unroll 8
    for (int c2 = 0; c2 < 256; ++c2) v += Wm[o * 256 + c2] * bv[c2];
    btot[o] = v;
  }
}

// ---- qw_gemm: qW[b][r=h*256+c][m] (bf16) = W2T × query + qb2 ; grid = B*4rt*128mt ------
__global__ __launch_bounds__(512)
void qw_gemm(const float* __restrict__ query, const unsigned short* __restrict__ W2T,
             const float* __restrict__ qb2, unsigned short* __restrict__ qWbuf) {
  __shared__ unsigned short Xl[32 * 256];
  const int tid = threadIdx.x;
  const int lane = tid & 63, wid = tid >> 6;
  const int wr = wid >> 1, wc = wid & 1;
  const int mt = blockIdx.x & 127;
  const int rt = (blockIdx.x >> 7) & 3;
  const int b = blockIdx.x >> 9;
  const int m0 = mt * 32;
  const float* Xb = query + (size_t)b * DM_ * M_ + m0;
  const int c4 = 4 * (tid & 7);
  const int ch0 = 4 * (tid >> 3);
  float4 f[4];
#pragma unroll
  for (int i = 0; i < 4; ++i) f[i] = *(const float4*)(Xb + (size_t)(ch0 + i) * M_ + c4);
#pragma unroll
  for (int j = 0; j < 4; ++j) {
    u16x4 u = { f2bf(((const float*)&f[0])[j]), f2bf(((const float*)&f[1])[j]),
                f2bf(((const float*)&f[2])[j]), f2bf(((const float*)&f[3])[j]) };
    *(u16x4*)((char*)Xl + swz512(c4 + j, 2 * ch0)) = u;
  }
  __syncthreads();
  f32x4 acc[4] = {};
  const int bcol = wc * 16 + (lane & 15);
  const int rdk = 16 * (lane >> 4);
  short8 a_cur[4], a_nxt[4];
#pragma unroll
  for (int fi = 0; fi < 4; ++fi)
    a_cur[fi] = *(const short8*)(W2T + (size_t)(((rt * 16 + wr * 4 + fi) * 64 + lane) * 8));
#pragma unroll
  for (int kgs = 0; kgs < 8; ++kgs) {
    if (kgs < 7) {
#pragma unroll
      for (int fi = 0; fi < 4; ++fi)
        a_nxt[fi] = *(const short8*)(W2T + (size_t)((((kgs + 1) * 64 + rt * 16 + wr * 4 + fi) * 64 + lane) * 8));
    }
    short8 bb = *(const short8*)((const char*)Xl + swz512(bcol, 64 * kgs + rdk));
#pragma unroll
    for (int fi = 0; fi < 4; ++fi)
      acc[fi] = __builtin_amdgcn_mfma_f32_16x16x32_bf16(a_cur[fi], bb, acc[fi], 0, 0, 0);
#pragma unroll
    for (int fi = 0; fi < 4; ++fi) a_cur[fi] = a_nxt[fi];
  }
#pragma unroll
  for (int fi = 0; fi < 4; ++fi) {
#pragma unroll
    for (int r = 0; r < 4; ++r) {
      const int rr = rt * 256 + wr * 64 + fi * 16 + (lane >> 4) * 4 + r;
      qWbuf[(size_t)(b * 1024 + rr) * M_ + m0 + bcol] = f2bf(acc[fi][r] + qb2[rr]);
    }
  }
}

// ---- fused_attn: scores + softmax + psum + PV + merge-GEMM -----------------------------
// grid = B*256 = 512 blocks (XCD-chunked), 1024 threads (16 waves), LDS 72 KB.
// KEY CHANGE vs R11: the score loop streams key AND value together; value is packed to
// bf16 and parked in registers (V[16] uint2 = 32 VGPR, fully-unrolled static indexing),
// so the PV pass runs from registers and the kernel has ONE long memory window instead
// of two separated by barrier-locked compute phases. launch_bounds(1024,4): 128-VGPR
// budget, no spill; 1 block/CU (overlap, not occupancy, is the lever per R9-R11).
__global__ __launch_bounds__(1024, 4)
void fused_attn(const float* __restrict__ key, const float* __restrict__ value,
                const unsigned short* __restrict__ qW, const unsigned short* __restrict__ Wmv,
                const float* __restrict__ btot, float* __restrict__ out,
                float* __restrict__ psum) {
  __shared__ float ldsA[16 * 64 * 17];   // 68 KB: qsl (score) | scx (reduce) | pvt (merge)
  __shared__ float ldsP[16 * 4 * 16];    // 4 KB prob [m'][h][kk]
  unsigned short* qsl = (unsigned short*)ldsA;
  const int tid = threadIdx.x;
  const int lane = tid & 63;
  const int w = tid >> 6;                                    // wave id 0..15
  const int vb = (blockIdx.x & 7) * 64 + (blockIdx.x >> 3);  // 512 = 8 XCD x 64
  const int b = vb >> 8;
  const int m0 = (vb & 255) * 16;
  // ---- stage qW slab: one (h,c) row per thread; [c][slot=(q+c)&15][h] rotation ----
  {
    const int c = tid & 255, h = tid >> 8;
    const unsigned short* src = qW + ((size_t)(b * 1024 + h * 256 + c)) * M_ + m0;
    uint4 rv[2];
    rv[0] = *(const uint4*)(src);
    rv[1] = *(const uint4*)(src + 8);
    const unsigned short* rs = (const unsigned short*)rv;
#pragma unroll
    for (int q = 0; q < 16; ++q) {
      const int slot = (q + c) & 15;
      qsl[c * 64 + slot * 4 + h] = rs[q];
    }
  }
  __syncthreads();
  const int mp = lane >> 2;              // m-local 0..15
  const int kkq = lane & 3;              // kk quarter
  const size_t cbase = (size_t)(b * 256) * 65536 + (size_t)m0 * 16 + lane * 4;
  // ---- combined K-score + V-prefetch pass: dense 1 KB wave-loads on BOTH streams ----
  f32x4 ps0 = {}, ps1 = {}, ps2 = {}, ps3 = {};
  uint2 Vb[16];                          // value parked as packed bf16 (32 VGPR)
#pragma unroll
  for (int i = 0; i < 16; ++i) {
    const int c = i * 16 + w;
    const f32x4 kv = *(const f32x4*)(key + cbase + (size_t)c * 65536);
    const f32x4 fv = *(const f32x4*)(value + cbase + (size_t)c * 65536);
    const int slot = (mp + c) & 15;
    const uint2 qv = *(const uint2*)&qsl[c * 64 + slot * 4];
    ps0 += kv * u2f(qv.x << 16);
    ps1 += kv * u2f(qv.x & 0xffff0000u);
    ps2 += kv * u2f(qv.y << 16);
    ps3 += kv * u2f(qv.y & 0xffff0000u);
    uint2 vbk;
    vbk.x = (uint32_t)f2bf(fv[0]) | ((uint32_t)f2bf(fv[1]) << 16);
    vbk.y = (uint32_t)f2bf(fv[2]) | ((uint32_t)f2bf(fv[3]) << 16);
    Vb[i] = vbk;
  }
  __syncthreads();                       // qsl dead -> scx takes over ldsA
  {
    float* scx = ldsA + w * 1088 + lane * 17;   // 17-pad: conflict-free b32 stores
#pragma unroll
    for (int j = 0; j < 4; ++j) {
      scx[j]      = ps0[j];
      scx[4 + j]  = ps1[j];
      scx[8 + j]  = ps2[j];
      scx[12 + j] = ps3[j];
    }
  }
  __syncthreads();
  // ---- reduce over 16 waves + softmax; thread t = m'(4b)|h(2b)|kk(4b) ----
  {
    const int mp2 = tid >> 6;
    const int h2 = (lane >> 4) & 3;
    const int kk = lane & 15;
    const int lanep = mp2 * 4 + (kk >> 2);
    const int idx = h2 * 4 + (kk & 3);
    float sc = 0.f;
#pragma unroll
    for (int w2 = 0; w2 < 16; ++w2) sc += ldsA[w2 * 1088 + lanep * 17 + idx];
    sc *= 0.125f;                        // 1/sqrt(64)
    float mx = sc;
    mx = fmaxf(mx, __shfl_xor(mx, 1)); mx = fmaxf(mx, __shfl_xor(mx, 2));
    mx = fmaxf(mx, __shfl_xor(mx, 4)); mx = fmaxf(mx, __shfl_xor(mx, 8));
    const float e = __expf(sc - mx);
    float sm = e;
    sm += __shfl_xor(sm, 1); sm += __shfl_xor(sm, 2);
    sm += __shfl_xor(sm, 4); sm += __shfl_xor(sm, 8);
    const float pb = e / sm;
    ldsP[(mp2 * 4 + h2) * 16 + kk] = pb;
    float tot = pb;
    tot += __shfl_xor(tot, 16); tot += __shfl_xor(tot, 32);
    if (lane < 16)                       // h2==0, lane==kk
      psum[((size_t)b * M_ + m0 + mp2) * KN_ + kk] = tot;
  }
  __syncthreads();                       // prob ready; scx dead -> pvt takes over ldsA
  // ---- PV pass: FROM REGISTERS (no global loads); pvt[m'][k=c*4+h] XOR-swizzled ----
  {
    const f32x4 pr0 = *(const f32x4*)&ldsP[(mp * 4 + 0) * 16 + kkq * 4];
    const f32x4 pr1 = *(const f32x4*)&ldsP[(mp * 4 + 1) * 16 + kkq * 4];
    const f32x4 pr2 = *(const f32x4*)&ldsP[(mp * 4 + 2) * 16 + kkq * 4];
    const f32x4 pr3 = *(const f32x4*)&ldsP[(mp * 4 + 3) * 16 + kkq * 4];
#pragma unroll
    for (int i = 0; i < 16; ++i) {
      const int c = i * 16 + w;
      f32x4 vv;
      vv[0] = u2f(Vb[i].x << 16); vv[1] = u2f(Vb[i].x & 0xffff0000u);
      vv[2] = u2f(Vb[i].y << 16); vv[3] = u2f(Vb[i].y & 0xffff0000u);
      float p0 = pr0[0] * vv[0] + pr0[1] * vv[1] + pr0[2] * vv[2] + pr0[3] * vv[3];
      float p1 = pr1[0] * vv[0] + pr1[1] * vv[1] + pr1[2] * vv[2] + pr1[3] * vv[3];
      float p2 = pr2[0] * vv[0] + pr2[1] * vv[1] + pr2[2] * vv[2] + pr2[3] * vv[3];
      float p3 = pr3[0] * vv[0] + pr3[1] * vv[1] + pr3[2] * vv[2] + pr3[3] * vv[3];
      p0 += __shfl_xor(p0, 1); p0 += __shfl_xor(p0, 2);
      p1 += __shfl_xor(p1, 1); p1 += __shfl_xor(p1, 2);
      p2 += __shfl_xor(p2, 1); p2 += __shfl_xor(p2, 2);
      p3 += __shfl_xor(p3, 1); p3 += __shfl_xor(p3, 2);
      if (kkq == 0) {
        uint2 o;
        o.x = (uint32_t)f2bf(p0) | ((uint32_t)f2bf(p1) << 16);
        o.y = (uint32_t)f2bf(p2) | ((uint32_t)f2bf(p3) << 16);
        *(uint2*)((char*)ldsA + ((mp * 2048 + c * 8) ^ ((mp & 7) << 4))) = o;
      }
    }
  }
  __syncthreads();
  // ---- merge GEMM: out[o][m'] = Wmv(256x1024) x pvt(1024x16) + btot ----
  {
    const int wid = tid >> 6;            // A-row-block (rows wid*16..+15)
    const int bcol = lane & 15;          // m'
    const int kgrp = lane >> 4;          // 0..3
    f32x4 acc = {};
    for (int kgs = 0; kgs < 32; ++kgs) {
      const int byte = (bcol * 2048 + kgs * 64 + kgrp * 16) ^ ((bcol & 7) << 4);
      const short8 bb = *(const short8*)((const char*)ldsA + byte);
      const short8 a0 = *(const short8*)(Wmv + (size_t)(((kgs * 16 + wid) * 64 + lane) * 8));
      acc = __builtin_amdgcn_mfma_f32_16x16x32_bf16(a0, bb, acc, 0, 0, 0);
    }
#pragma unroll
    for (int r = 0; r < 4; ++r) {
      const int o = wid * 16 + kgrp * 4 + r;
      out[((size_t)(b * DM_ + o)) * M_ + m0 + bcol] = acc[r] + btot[o];
    }
  }
}

extern "C" void kernel_launch(void* const* d_in, const int* in_sizes, int n_in,
                              void* d_out, int out_size, void* d_ws, size_t ws_size,
                              hipStream_t stream) {
  const float* query = (const float*)d_in[0];
  const float* key   = (const float*)d_in[1];
  const float* value = (const float*)d_in[2];
  const float* Wq = (const float*)d_in[3];
  const float* bq = (const float*)d_in[4];
  const float* Wk = (const float*)d_in[5];
  const float* bk = (const float*)d_in[6];  (void)bk;  // folded: softmax-invariant
  const float* Wv = (const float*)d_in[7];
  const float* bv = (const float*)d_in[8];
  const float* Wm = (const float*)d_in[9];
  const float* bm = (const float*)d_in[10];
  float* out  = (float*)d_out;
  float* psum = out + (size_t)B_ * DM_ * M_;   // outputs concatenated: out then prob_sum

  // ---- workspace layout (17.8 MB) ----
  const size_t Wmv_off  = 524288;
  const size_t qb2_off  = 1048576;
  const size_t btot_off = 1052672;
  const size_t qW_off   = 1053696;             // qW: 16.78 MB bf16

  unsigned short* W2T   = (unsigned short*)d_ws;
  unsigned short* Wmv   = (unsigned short*)((char*)d_ws + Wmv_off);
  float* qb2            = (float*)((char*)d_ws + qb2_off);
  float* btot           = (float*)((char*)d_ws + btot_off);
  unsigned short* qWbuf = (unsigned short*)((char*)d_ws + qW_off);

  prep2<<<dim3(1027), dim3(512), 0, stream>>>(Wq, bq, Wk, Wv, bv, Wm, bm, W2T, Wmv, qb2, btot);
  qw_gemm<<<dim3(B_ * 4 * 128), dim3(512), 0, stream>>>(query, W2T, qb2, qWbuf);
  fused_attn<<<dim3(512), dim3(1024), 0, stream>>>(key, value, qWbuf, Wmv, btot, out, psum);
}

// Round 13
// 112.418 us; speedup vs baseline: 1.0204x; 1.0204x over previous
//
#include <hip/hip_runtime.h>
#include <stdint.h>

#define DM_ 256
#define H_ 4
#define M_ 4096
#define KN_ 16
#define B_ 2
#define MK_ (M_*KN_)

typedef __attribute__((ext_vector_type(8))) short short8;
typedef __attribute__((ext_vector_type(4))) float f32x4;
typedef __attribute__((ext_vector_type(4))) unsigned short u16x4;

static __device__ __forceinline__ unsigned short f2bf(float x) {
  union { float f; uint32_t u; } v; v.f = x;
  uint32_t u = v.u + (0x7FFFu + ((v.u >> 16) & 1u));  // RNE
  return (unsigned short)(u >> 16);
}
static __device__ __forceinline__ float u2f(uint32_t u) {
  union { uint32_t u; float f; } v; v.u = u; return v.f;
}

// XOR swizzle for [col][k] bf16 tiles (row stride 512 B), bank-floor b128 reads/writes.
static __device__ __forceinline__ int swz512(int col, int kbyte) {
  int f = ((col >> 2) & 7) ^ ((col & 1) << 2);
  return (col << 9) + (kbyte ^ (f << 4));
}

// ---- prep2: weight products, fragment-linear bf16, fused biases ------------------------
__global__ void prep2(const float* __restrict__ Wq, const float* __restrict__ bq,
                      const float* __restrict__ Wk, const float* __restrict__ Wv,
                      const float* __restrict__ bv, const float* __restrict__ Wm,
                      const float* __restrict__ bm,
                      unsigned short* __restrict__ W2T, unsigned short* __restrict__ Wmv,
                      float* __restrict__ qb2, float* __restrict__ btot) {
  int t = blockIdx.x * 512 + threadIdx.x;
  if (t < 262144) {                       // W2T fragment-linear [kstep8][rowblk64][lane][8]
    int j = t & 7, lane = (t >> 3) & 63, rowblk = (t >> 9) & 63, kstep = t >> 15;
    int row = rowblk * 16 + (lane & 15);
    int k = kstep * 32 + (lane >> 4) * 8 + j;
    int h = row >> 8, c = row & 255;
    float v = 0.f;
#pragma unroll 8
    for (int d = 0; d < 64; ++d) v += Wq[(4 * d + h) * 256 + k] * Wk[(4 * d + h) * 256 + c];
    W2T[t] = f2bf(v);
  } else if (t < 524288) {                // Wmv fragment-linear [kstep32][rowblk16][lane][8]
    int e = t - 262144;
    int j = e & 7, lane = (e >> 3) & 63, rowblk = (e >> 9) & 15, kstep = e >> 13;
    int o = rowblk * 16 + (lane & 15);
    int kidx = kstep * 32 + (lane >> 4) * 8 + j;
    int c = kidx >> 2, h = kidx & 3;
    float v = 0.f;
#pragma unroll 8
    for (int d = 0; d < 64; ++d) v += Wm[o * 256 + 4 * d + h] * Wv[(4 * d + h) * 256 + c];
    Wmv[e] = f2bf(v);
  } else if (t < 525312) {
    int r = t - 524288; int h = r >> 8, c = r & 255;
    float v = 0.f;
#pragma unroll 8
    for (int d = 0; d < 64; ++d) v += bq[4 * d + h] * Wk[(4 * d + h) * 256 + c];
    qb2[r] = v;
  } else if (t < 525568) {
    int o = t - 525312;
    float v = bm[o];
#pragma unroll 8
    for (int c2 = 0; c2 < 256; ++c2) v += Wm[o * 256 + c2] * bv[c2];
    btot[o] = v;
  }
}

// ---- qw_gemm: qW[b][r=h*256+c][m] (bf16) = W2T × query + qb2 ; grid = B*4rt*128mt ------
__global__ __launch_bounds__(512)
void qw_gemm(const float* __restrict__ query, const unsigned short* __restrict__ W2T,
             const float* __restrict__ qb2, unsigned short* __restrict__ qWbuf) {
  __shared__ unsigned short Xl[32 * 256];
  const int tid = threadIdx.x;
  const int lane = tid & 63, wid = tid >> 6;
  const int wr = wid >> 1, wc = wid & 1;
  const int mt = blockIdx.x & 127;
  const int rt = (blockIdx.x >> 7) & 3;
  const int b = blockIdx.x >> 9;
  const int m0 = mt * 32;
  const float* Xb = query + (size_t)b * DM_ * M_ + m0;
  const int c4 = 4 * (tid & 7);
  const int ch0 = 4 * (tid >> 3);
  float4 f[4];
#pragma unroll
  for (int i = 0; i < 4; ++i) f[i] = *(const float4*)(Xb + (size_t)(ch0 + i) * M_ + c4);
#pragma unroll
  for (int j = 0; j < 4; ++j) {
    u16x4 u = { f2bf(((const float*)&f[0])[j]), f2bf(((const float*)&f[1])[j]),
                f2bf(((const float*)&f[2])[j]), f2bf(((const float*)&f[3])[j]) };
    *(u16x4*)((char*)Xl + swz512(c4 + j, 2 * ch0)) = u;
  }
  __syncthreads();
  f32x4 acc[4] = {};
  const int bcol = wc * 16 + (lane & 15);
  const int rdk = 16 * (lane >> 4);
  short8 a_cur[4], a_nxt[4];
#pragma unroll
  for (int fi = 0; fi < 4; ++fi)
    a_cur[fi] = *(const short8*)(W2T + (size_t)(((rt * 16 + wr * 4 + fi) * 64 + lane) * 8));
#pragma unroll
  for (int kgs = 0; kgs < 8; ++kgs) {
    if (kgs < 7) {
#pragma unroll
      for (int fi = 0; fi < 4; ++fi)
        a_nxt[fi] = *(const short8*)(W2T + (size_t)((((kgs + 1) * 64 + rt * 16 + wr * 4 + fi) * 64 + lane) * 8));
    }
    short8 bb = *(const short8*)((const char*)Xl + swz512(bcol, 64 * kgs + rdk));
#pragma unroll
    for (int fi = 0; fi < 4; ++fi)
      acc[fi] = __builtin_amdgcn_mfma_f32_16x16x32_bf16(a_cur[fi], bb, acc[fi], 0, 0, 0);
#pragma unroll
    for (int fi = 0; fi < 4; ++fi) a_cur[fi] = a_nxt[fi];
  }
#pragma unroll
  for (int fi = 0; fi < 4; ++fi) {
#pragma unroll
    for (int r = 0; r < 4; ++r) {
      const int rr = rt * 256 + wr * 64 + fi * 16 + (lane >> 4) * 4 + r;
      qWbuf[(size_t)(b * 1024 + rr) * M_ + m0 + bcol] = f2bf(acc[fi][r] + qb2[rr]);
    }
  }
}

// ---- fused_attn: scores + softmax + psum + PV + merge-GEMM -----------------------------
// grid = B*256 = 512 blocks (XCD-chunked), 1024 threads (16 waves).
// KEY CHANGE vs R12: K and V are streamed through a double-buffered LDS region via
// global_load_lds (fire-and-forget DMA): one instruction stages one channel's full 1 KB
// row (wave-uniform dest, lane x 16B, LINEAR). Counted s_waitcnt vmcnt(2) + raw s_barrier
// per 32-channel chunk keeps a guaranteed-deep per-CU load queue (~64 KB in flight) that
// the compiler cannot shrink (no dest VGPRs). Never vmcnt(0) in the steady-state loop.
__global__ __launch_bounds__(1024, 4)
void fused_attn(const float* __restrict__ key, const float* __restrict__ value,
                const unsigned short* __restrict__ qW, const unsigned short* __restrict__ Wmv,
                const float* __restrict__ btot, float* __restrict__ out,
                float* __restrict__ psum) {
  // [0,65536): stream dbuf (2 halves x 32 chan x 1KB)   [aliased by scx f32[16][64][17] post-K]
  // [65536,98304): qsl (score) -> pvt (PV/merge), 32 KB
  // [98304,102400): ldsP prob f32[16][4][16]
  __shared__ __align__(16) char LDS[102400];
  unsigned short* qsl = (unsigned short*)(LDS + 65536);
  float* scxp = (float*)LDS;
  float* ldsP = (float*)(LDS + 98304);
  const int tid = threadIdx.x;
  const int lane = tid & 63;
  const int w = tid >> 6;                                    // wave id 0..15
  const int vb = (blockIdx.x & 7) * 64 + (blockIdx.x >> 3);  // 512 = 8 XCD x 64
  const int b = vb >> 8;
  const int m0 = (vb & 255) * 16;
  // ---- stage qW slab: one (h,c) row per thread; [c][slot=(q+c)&15][h] rotation ----
  {
    const int c = tid & 255, h = tid >> 8;
    const unsigned short* src = qW + ((size_t)(b * 1024 + h * 256 + c)) * M_ + m0;
    uint4 rv[2];
    rv[0] = *(const uint4*)(src);
    rv[1] = *(const uint4*)(src + 8);
    const unsigned short* rs = (const unsigned short*)rv;
#pragma unroll
    for (int q = 0; q < 16; ++q) {
      const int slot = (q + c) & 15;
      qsl[c * 64 + slot * 4 + h] = rs[q];
    }
  }
  __syncthreads();                       // also drains vmcnt: clean queue baseline
  const int mp = lane >> 2;              // m-local 0..15
  const int kkq = lane & 3;              // kk quarter
  const float* ksrc = key   + (size_t)(b * 256) * 65536 + (size_t)m0 * 16 + lane * 4;
  const float* vsrc = value + (size_t)(b * 256) * 65536 + (size_t)m0 * 16 + lane * 4;
  // issue chunk i of stream src: wave w stages channels i*32 + w*2 + {0,1}
  auto issue2 = [&](const float* src, int i) {
    const int h = i & 1;
#pragma unroll
    for (int j = 0; j < 2; ++j) {
      const int r = w * 2 + j;
      __builtin_amdgcn_global_load_lds(
          (const __attribute__((address_space(1))) uint32_t*)(src + (size_t)(i * 32 + r) * 65536),
          (__attribute__((address_space(3))) uint32_t*)(LDS + h * 32768 + r * 1024),
          16, 0, 0);
    }
  };
  f32x4 ps0 = {}, ps1 = {}, ps2 = {}, ps3 = {};
  auto scoreChunk = [&](int i) {
    const int h = i & 1;
#pragma unroll
    for (int j = 0; j < 2; ++j) {
      const int r = w * 2 + j;
      const int c = i * 32 + r;
      const f32x4 kv = *(const f32x4*)(LDS + h * 32768 + r * 1024 + lane * 16);
      const int slot = (mp + c) & 15;
      const uint2 qv = *(const uint2*)&qsl[c * 64 + slot * 4];
      ps0 += kv * u2f(qv.x << 16);
      ps1 += kv * u2f(qv.x & 0xffff0000u);
      ps2 += kv * u2f(qv.y << 16);
      ps3 += kv * u2f(qv.y & 0xffff0000u);
    }
  };
  // ---- K streaming: 8 chunks, counted-vmcnt pipeline ----
  issue2(ksrc, 0);
#pragma unroll 1
  for (int i = 0; i < 7; ++i) {
    issue2(ksrc, i + 1);
    __builtin_amdgcn_sched_barrier(0);
    asm volatile("s_waitcnt vmcnt(2)" ::: "memory");
    __builtin_amdgcn_sched_barrier(0);
    __builtin_amdgcn_s_barrier();
    scoreChunk(i);
    __builtin_amdgcn_s_barrier();
    asm volatile("" ::: "memory");
  }
  asm volatile("s_waitcnt vmcnt(0)" ::: "memory");
  __builtin_amdgcn_sched_barrier(0);
  __builtin_amdgcn_s_barrier();
  scoreChunk(7);
  __syncthreads();                       // buf+qsl(head) dead -> scx takes over
  {
    float* scx = scxp + w * 1088 + lane * 17;   // 17-pad: conflict-free b32 stores
#pragma unroll
    for (int j = 0; j < 4; ++j) {
      scx[j]      = ps0[j];
      scx[4 + j]  = ps1[j];
      scx[8 + j]  = ps2[j];
      scx[12 + j] = ps3[j];
    }
  }
  __syncthreads();
  // ---- reduce over 16 waves + softmax; thread t = m'(4b)|h(2b)|kk(4b) ----
  {
    const int mp2 = tid >> 6;
    const int h2 = (lane >> 4) & 3;
    const int kk = lane & 15;
    const int lanep = mp2 * 4 + (kk >> 2);
    const int idx = h2 * 4 + (kk & 3);
    float sc = 0.f;
#pragma unroll
    for (int w2 = 0; w2 < 16; ++w2) sc += scxp[w2 * 1088 + lanep * 17 + idx];
    sc *= 0.125f;                        // 1/sqrt(64)
    float mx = sc;
    mx = fmaxf(mx, __shfl_xor(mx, 1)); mx = fmaxf(mx, __shfl_xor(mx, 2));
    mx = fmaxf(mx, __shfl_xor(mx, 4)); mx = fmaxf(mx, __shfl_xor(mx, 8));
    const float e = __expf(sc - mx);
    float sm = e;
    sm += __shfl_xor(sm, 1); sm += __shfl_xor(sm, 2);
    sm += __shfl_xor(sm, 4); sm += __shfl_xor(sm, 8);
    const float pb = e / sm;
    ldsP[(mp2 * 4 + h2) * 16 + kk] = pb;
    float tot = pb;
    tot += __shfl_xor(tot, 16); tot += __shfl_xor(tot, 32);
    if (lane < 16)                       // h2==0, lane==kk
      psum[((size_t)b * M_ + m0 + mp2) * KN_ + kk] = tot;
  }
  __syncthreads();                       // drains psum store: V queue counts clean
  // ---- V streaming + PV: same pipeline; pvt[m'][k=c*4+h] XOR-swizzled at +65536 ----
  const f32x4 pr0 = *(const f32x4*)&ldsP[(mp * 4 + 0) * 16 + kkq * 4];
  const f32x4 pr1 = *(const f32x4*)&ldsP[(mp * 4 + 1) * 16 + kkq * 4];
  const f32x4 pr2 = *(const f32x4*)&ldsP[(mp * 4 + 2) * 16 + kkq * 4];
  const f32x4 pr3 = *(const f32x4*)&ldsP[(mp * 4 + 3) * 16 + kkq * 4];
  auto pvChunk = [&](int i) {
    const int h = i & 1;
#pragma unroll
    for (int j = 0; j < 2; ++j) {
      const int r = w * 2 + j;
      const int c = i * 32 + r;
      const f32x4 vv = *(const f32x4*)(LDS + h * 32768 + r * 1024 + lane * 16);
      float p0 = pr0[0] * vv[0] + pr0[1] * vv[1] + pr0[2] * vv[2] + pr0[3] * vv[3];
      float p1 = pr1[0] * vv[0] + pr1[1] * vv[1] + pr1[2] * vv[2] + pr1[3] * vv[3];
      float p2 = pr2[0] * vv[0] + pr2[1] * vv[1] + pr2[2] * vv[2] + pr2[3] * vv[3];
      float p3 = pr3[0] * vv[0] + pr3[1] * vv[1] + pr3[2] * vv[2] + pr3[3] * vv[3];
      p0 += __shfl_xor(p0, 1); p0 += __shfl_xor(p0, 2);
      p1 += __shfl_xor(p1, 1); p1 += __shfl_xor(p1, 2);
      p2 += __shfl_xor(p2, 1); p2 += __shfl_xor(p2, 2);
      p3 += __shfl_xor(p3, 1); p3 += __shfl_xor(p3, 2);
      if (kkq == 0) {
        uint2 o;
        o.x = (uint32_t)f2bf(p0) | ((uint32_t)f2bf(p1) << 16);
        o.y = (uint32_t)f2bf(p2) | ((uint32_t)f2bf(p3) << 16);
        *(uint2*)(LDS + 65536 + ((mp * 2048 + c * 8) ^ ((mp & 7) << 4))) = o;
      }
    }
  };
  issue2(vsrc, 0);
#pragma unroll 1
  for (int i = 0; i < 7; ++i) {
    issue2(vsrc, i + 1);
    __builtin_amdgcn_sched_barrier(0);
    asm volatile("s_waitcnt vmcnt(2)" ::: "memory");
    __builtin_amdgcn_sched_barrier(0);
    __builtin_amdgcn_s_barrier();
    pvChunk(i);
    __builtin_amdgcn_s_barrier();
    asm volatile("" ::: "memory");
  }
  asm volatile("s_waitcnt vmcnt(0)" ::: "memory");
  __builtin_amdgcn_sched_barrier(0);
  __builtin_amdgcn_s_barrier();
  pvChunk(7);
  __syncthreads();                       // pvt writes visible
  // ---- merge GEMM: out[o][m'] = Wmv(256x1024) x pvt(1024x16) + btot ----
  {
    const int wid = tid >> 6;            // A-row-block (rows wid*16..+15)
    const int bcol = lane & 15;          // m'
    const int kgrp = lane >> 4;          // 0..3
    f32x4 acc = {};
    for (int kgs = 0; kgs < 32; ++kgs) {
      const int byte = 65536 + (((bcol * 2048 + kgs * 64 + kgrp * 16)) ^ ((bcol & 7) << 4));
      const short8 bb = *(const short8*)(LDS + byte);
      const short8 a0 = *(const short8*)(Wmv + (size_t)(((kgs * 16 + wid) * 64 + lane) * 8));
      acc = __builtin_amdgcn_mfma_f32_16x16x32_bf16(a0, bb, acc, 0, 0, 0);
    }
#pragma unroll
    for (int r = 0; r < 4; ++r) {
      const int o = wid * 16 + kgrp * 4 + r;
      out[((size_t)(b * DM_ + o)) * M_ + m0 + bcol] = acc[r] + btot[o];
    }
  }
}

extern "C" void kernel_launch(void* const* d_in, const int* in_sizes, int n_in,
                              void* d_out, int out_size, void* d_ws, size_t ws_size,
                              hipStream_t stream) {
  const float* query = (const float*)d_in[0];
  const float* key   = (const float*)d_in[1];
  const float* value = (const float*)d_in[2];
  const float* Wq = (const float*)d_in[3];
  const float* bq = (const float*)d_in[4];
  const float* Wk = (const float*)d_in[5];
  const float* bk = (const float*)d_in[6];  (void)bk;  // folded: softmax-invariant
  const float* Wv = (const float*)d_in[7];
  const float* bv = (const float*)d_in[8];
  const float* Wm = (const float*)d_in[9];
  const float* bm = (const float*)d_in[10];
  float* out  = (float*)d_out;
  float* psum = out + (size_t)B_ * DM_ * M_;   // outputs concatenated: out then prob_sum

  // ---- workspace layout (17.8 MB) ----
  const size_t Wmv_off  = 524288;
  const size_t qb2_off  = 1048576;
  const size_t btot_off = 1052672;
  const size_t qW_off   = 1053696;             // qW: 16.78 MB bf16

  unsigned short* W2T   = (unsigned short*)d_ws;
  unsigned short* Wmv   = (unsigned short*)((char*)d_ws + Wmv_off);
  float* qb2            = (float*)((char*)d_ws + qb2_off);
  float* btot           = (float*)((char*)d_ws + btot_off);
  unsigned short* qWbuf = (unsigned short*)((char*)d_ws + qW_off);

  prep2<<<dim3(1027), dim3(512), 0, stream>>>(Wq, bq, Wk, Wv, bv, Wm, bm, W2T, Wmv, qb2, btot);
  qw_gemm<<<dim3(B_ * 4 * 128), dim3(512), 0, stream>>>(query, W2T, qb2, qWbuf);
  fused_attn<<<dim3(512), dim3(1024), 0, stream>>>(key, value, qWbuf, Wmv, btot, out, psum);
}

// Round 14
// 109.230 us; speedup vs baseline: 1.0502x; 1.0292x over previous
//
#include <hip/hip_runtime.h>
#include <stdint.h>

#define DM_ 256
#define H_ 4
#define M_ 4096
#define KN_ 16
#define B_ 2
#define MK_ (M_*KN_)

typedef __attribute__((ext_vector_type(8))) short short8;
typedef __attribute__((ext_vector_type(4))) float f32x4;
typedef __attribute__((ext_vector_type(4))) unsigned short u16x4;

static __device__ __forceinline__ unsigned short f2bf(float x) {
  union { float f; uint32_t u; } v; v.f = x;
  uint32_t u = v.u + (0x7FFFu + ((v.u >> 16) & 1u));  // RNE
  return (unsigned short)(u >> 16);
}
static __device__ __forceinline__ float u2f(uint32_t u) {
  union { uint32_t u; float f; } v; v.u = u; return v.f;
}

// XOR swizzle for [col][k] bf16 tiles (row stride 512 B), bank-floor b128 reads/writes.
static __device__ __forceinline__ int swz512(int col, int kbyte) {
  int f = ((col >> 2) & 7) ^ ((col & 1) << 2);
  return (col << 9) + (kbyte ^ (f << 4));
}

// ---- prep2: weight products, fragment-linear bf16, fused biases ------------------------
__global__ void prep2(const float* __restrict__ Wq, const float* __restrict__ bq,
                      const float* __restrict__ Wk, const float* __restrict__ Wv,
                      const float* __restrict__ bv, const float* __restrict__ Wm,
                      const float* __restrict__ bm,
                      unsigned short* __restrict__ W2T, unsigned short* __restrict__ Wmv,
                      float* __restrict__ qb2, float* __restrict__ btot) {
  int t = blockIdx.x * 512 + threadIdx.x;
  if (t < 262144) {                       // W2T fragment-linear [kstep8][rowblk64][lane][8]
    int j = t & 7, lane = (t >> 3) & 63, rowblk = (t >> 9) & 63, kstep = t >> 15;
    int row = rowblk * 16 + (lane & 15);
    int k = kstep * 32 + (lane >> 4) * 8 + j;
    int h = row >> 8, c = row & 255;
    float v = 0.f;
#pragma unroll 8
    for (int d = 0; d < 64; ++d) v += Wq[(4 * d + h) * 256 + k] * Wk[(4 * d + h) * 256 + c];
    W2T[t] = f2bf(v);
  } else if (t < 524288) {                // Wmv fragment-linear [kstep32][rowblk16][lane][8]
    int e = t - 262144;
    int j = e & 7, lane = (e >> 3) & 63, rowblk = (e >> 9) & 15, kstep = e >> 13;
    int o = rowblk * 16 + (lane & 15);
    int kidx = kstep * 32 + (lane >> 4) * 8 + j;
    int c = kidx >> 2, h = kidx & 3;
    float v = 0.f;
#pragma unroll 8
    for (int d = 0; d < 64; ++d) v += Wm[o * 256 + 4 * d + h] * Wv[(4 * d + h) * 256 + c];
    Wmv[e] = f2bf(v);
  } else if (t < 525312) {
    int r = t - 524288; int h = r >> 8, c = r & 255;
    float v = 0.f;
#pragma unroll 8
    for (int d = 0; d < 64; ++d) v += bq[4 * d + h] * Wk[(4 * d + h) * 256 + c];
    qb2[r] = v;
  } else if (t < 525568) {
    int o = t - 525312;
    float v = bm[o];
#pragma unroll 8
    for (int c2 = 0; c2 < 256; ++c2) v += Wm[o * 256 + c2] * bv[c2];
    btot[o] = v;
  }
}

// ---- qw_gemm: qW[b][r=h*256+c][m] (bf16) = W2T × query + qb2 ; grid = B*4rt*128mt ------
__global__ __launch_bounds__(512)
void qw_gemm(const float* __restrict__ query, const unsigned short* __restrict__ W2T,
             const float* __restrict__ qb2, unsigned short* __restrict__ qWbuf) {
  __shared__ unsigned short Xl[32 * 256];
  const int tid = threadIdx.x;
  const int lane = tid & 63, wid = tid >> 6;
  const int wr = wid >> 1, wc = wid & 1;
  const int mt = blockIdx.x & 127;
  const int rt = (blockIdx.x >> 7) & 3;
  const int b = blockIdx.x >> 9;
  const int m0 = mt * 32;
  const float* Xb = query + (size_t)b * DM_ * M_ + m0;
  const int c4 = 4 * (tid & 7);
  const int ch0 = 4 * (tid >> 3);
  float4 f[4];
#pragma unroll
  for (int i = 0; i < 4; ++i) f[i] = *(const float4*)(Xb + (size_t)(ch0 + i) * M_ + c4);
#pragma unroll
  for (int j = 0; j < 4; ++j) {
    u16x4 u = { f2bf(((const float*)&f[0])[j]), f2bf(((const float*)&f[1])[j]),
                f2bf(((const float*)&f[2])[j]), f2bf(((const float*)&f[3])[j]) };
    *(u16x4*)((char*)Xl + swz512(c4 + j, 2 * ch0)) = u;
  }
  __syncthreads();
  f32x4 acc[4] = {};
  const int bcol = wc * 16 + (lane & 15);
  const int rdk = 16 * (lane >> 4);
  short8 a_cur[4], a_nxt[4];
#pragma unroll
  for (int fi = 0; fi < 4; ++fi)
    a_cur[fi] = *(const short8*)(W2T + (size_t)(((rt * 16 + wr * 4 + fi) * 64 + lane) * 8));
#pragma unroll
  for (int kgs = 0; kgs < 8; ++kgs) {
    if (kgs < 7) {
#pragma unroll
      for (int fi = 0; fi < 4; ++fi)
        a_nxt[fi] = *(const short8*)(W2T + (size_t)((((kgs + 1) * 64 + rt * 16 + wr * 4 + fi) * 64 + lane) * 8));
    }
    short8 bb = *(const short8*)((const char*)Xl + swz512(bcol, 64 * kgs + rdk));
#pragma unroll
    for (int fi = 0; fi < 4; ++fi)
      acc[fi] = __builtin_amdgcn_mfma_f32_16x16x32_bf16(a_cur[fi], bb, acc[fi], 0, 0, 0);
#pragma unroll
    for (int fi = 0; fi < 4; ++fi) a_cur[fi] = a_nxt[fi];
  }
#pragma unroll
  for (int fi = 0; fi < 4; ++fi) {
#pragma unroll
    for (int r = 0; r < 4; ++r) {
      const int rr = rt * 256 + wr * 64 + fi * 16 + (lane >> 4) * 4 + r;
      qWbuf[(size_t)(b * 1024 + rr) * M_ + m0 + bcol] = f2bf(acc[fi][r] + qb2[rr]);
    }
  }
}

// ---- fused_attn: scores + softmax + PV + merge-GEMM + psum -----------------------------
// grid = B*256 = 512 blocks (XCD-chunked), 1024 threads (16 waves).
// KEY CHANGE vs R13: streaming is BARRIER-FREE. Each wave owns a private depth-3 ring
// (3 x 1 KB LDS slots) and free-runs {wait vmcnt(2) -> consume own channel -> issue next
// DMA into freed slot} over its 16 channels (c = w*16+i). No cross-wave sharing in the
// stream loops => no barriers => waves self-skew and the CU keeps 32-48 KB of DMA
// continuously in flight. Only 4 raw s_barriers remain (softmax/merge phase edges),
// crossed with the V-ring prefill outstanding (vmcnt NOT drained).
// LDS plan (132 KB, phase-aliased):
//   [0,49152)      K-ring (wave w at w*3072)      -> scx f32[16][64][16] at [0,65536)
//   [49152,81920)  qsl 32 KB (score)              -> pvt 32 KB (PV/merge)
//   [81920,131072) V-ring (wave w at w*3072)
//   [131072,135168) prob f32[16][4][16]
__global__ __launch_bounds__(1024, 4)
void fused_attn(const float* __restrict__ key, const float* __restrict__ value,
                const unsigned short* __restrict__ qW, const unsigned short* __restrict__ Wmv,
                const float* __restrict__ btot, float* __restrict__ out,
                float* __restrict__ psum) {
  __shared__ __align__(16) char LDS[135168];
  const int KRING = 0, QSL = 49152, SCX = 0, PVT = 49152, VRING = 81920, PROB = 131072;
  unsigned short* qsl = (unsigned short*)(LDS + QSL);
  float* ldsP = (float*)(LDS + PROB);
  const int tid = threadIdx.x;
  const int lane = tid & 63;
  const int w = tid >> 6;                                    // wave id 0..15
  const int vb = (blockIdx.x & 7) * 64 + (blockIdx.x >> 3);  // 512 = 8 XCD x 64
  const int b = vb >> 8;
  const int m0 = (vb & 255) * 16;
  // ---- stage qW slab: one (h,c) row per thread; [c][slot=(q+c)&15][h] rotation ----
  {
    const int c = tid & 255, h = tid >> 8;
    const unsigned short* src = qW + ((size_t)(b * 1024 + h * 256 + c)) * M_ + m0;
    uint4 rv[2];
    rv[0] = *(const uint4*)(src);
    rv[1] = *(const uint4*)(src + 8);
    const unsigned short* rs = (const unsigned short*)rv;
#pragma unroll
    for (int q = 0; q < 16; ++q) {
      const int slot = (q + c) & 15;
      qsl[c * 64 + slot * 4 + h] = rs[q];
    }
  }
  __syncthreads();                       // drains all counters: clean vmcnt baseline
  const int mp = lane >> 2;              // m-local 0..15
  const int kkq = lane & 3;              // kk quarter
  const float* ksrc = key   + (size_t)(b * 256) * 65536 + (size_t)m0 * 16 + lane * 4;
  const float* vsrc = value + (size_t)(b * 256) * 65536 + (size_t)m0 * 16 + lane * 4;
  f32x4 ps0 = {}, ps1 = {}, ps2 = {}, ps3 = {};

#define KISS(ch, slot) \
  __builtin_amdgcn_global_load_lds( \
      (const __attribute__((address_space(1))) uint32_t*)(ksrc + (size_t)(w * 16 + (ch)) * 65536), \
      (__attribute__((address_space(3))) uint32_t*)(LDS + KRING + w * 3072 + (slot) * 1024), 16, 0, 0)
#define VISS(ch, slot) \
  __builtin_amdgcn_global_load_lds( \
      (const __attribute__((address_space(1))) uint32_t*)(vsrc + (size_t)(w * 16 + (ch)) * 65536), \
      (__attribute__((address_space(3))) uint32_t*)(LDS + VRING + w * 3072 + (slot) * 1024), 16, 0, 0)
#define KCONS(i, slot, n) { \
    asm volatile("s_waitcnt vmcnt(" #n ")" ::: "memory"); \
    __builtin_amdgcn_sched_barrier(0); \
    const int c = w * 16 + (i); \
    const f32x4 kv = *(const f32x4*)(LDS + KRING + w * 3072 + (slot) * 1024 + lane * 16); \
    const uint2 qv = *(const uint2*)&qsl[c * 64 + (((mp + c) & 15)) * 4]; \
    ps0 += kv * u2f(qv.x << 16); \
    ps1 += kv * u2f(qv.x & 0xffff0000u); \
    ps2 += kv * u2f(qv.y << 16); \
    ps3 += kv * u2f(qv.y & 0xffff0000u); \
  }
  // ---- K stream: per-wave private ring, barrier-free ----
  KISS(0, 0); KISS(1, 1); KISS(2, 2);
  KCONS(0, 0, 2)  KISS(3, 0);
  KCONS(1, 1, 2)  KISS(4, 1);
  KCONS(2, 2, 2)  KISS(5, 2);
  KCONS(3, 0, 2)  KISS(6, 0);
  KCONS(4, 1, 2)  KISS(7, 1);
  KCONS(5, 2, 2)  KISS(8, 2);
  KCONS(6, 0, 2)  KISS(9, 0);
  KCONS(7, 1, 2)  KISS(10, 1);
  KCONS(8, 2, 2)  KISS(11, 2);
  KCONS(9, 0, 2)  KISS(12, 0);
  KCONS(10, 1, 2) KISS(13, 1);
  KCONS(11, 2, 2) KISS(14, 2);
  KCONS(12, 0, 2) KISS(15, 0);
  KCONS(13, 1, 2)
  KCONS(14, 2, 1)
  KCONS(15, 0, 0)
  // ---- V-ring prefill: 3 DMAs in flight across the softmax phase ----
  VISS(0, 0); VISS(1, 1); VISS(2, 2);
  __builtin_amdgcn_s_barrier();          // all waves left K loop (qsl/K-ring dead)
  // ---- scx write: [w][lane row][16 f32], slot-swizzled b128 stores ----
  {
    char* base = LDS + SCX + w * 4096 + lane * 64;
    const int sw = (lane >> 1) & 3;
    *(f32x4*)(base + ((0 ^ sw) << 4)) = ps0;
    *(f32x4*)(base + ((1 ^ sw) << 4)) = ps1;
    *(f32x4*)(base + ((2 ^ sw) << 4)) = ps2;
    *(f32x4*)(base + ((3 ^ sw) << 4)) = ps3;
  }
  asm volatile("s_waitcnt lgkmcnt(0)" ::: "memory");
  __builtin_amdgcn_s_barrier();
  // ---- reduce over 16 waves + softmax; thread t = m'(4b=wave)|h(2b)|kk(4b) ----
  {
    const int mp2 = tid >> 6;
    const int h2 = (lane >> 4) & 3;
    const int kk = lane & 15;
    const int lanep = mp2 * 4 + (kk >> 2);
    const int slotr = h2 ^ ((lanep >> 1) & 3);
    const int off = SCX + lanep * 64 + (slotr << 4) + (kk & 3) * 4;
    float sc = 0.f;
#pragma unroll
    for (int w2 = 0; w2 < 16; ++w2) sc += *(const float*)(LDS + w2 * 4096 + off);
    sc *= 0.125f;                        // 1/sqrt(64)
    float mx = sc;
    mx = fmaxf(mx, __shfl_xor(mx, 1)); mx = fmaxf(mx, __shfl_xor(mx, 2));
    mx = fmaxf(mx, __shfl_xor(mx, 4)); mx = fmaxf(mx, __shfl_xor(mx, 8));
    const float e = __expf(sc - mx);
    float sm = e;
    sm += __shfl_xor(sm, 1); sm += __shfl_xor(sm, 2);
    sm += __shfl_xor(sm, 4); sm += __shfl_xor(sm, 8);
    ldsP[(mp2 * 4 + h2) * 16 + kk] = e / sm;
  }
  asm volatile("s_waitcnt lgkmcnt(0)" ::: "memory");
  __builtin_amdgcn_s_barrier();
  // ---- V stream + PV: per-wave private ring, barrier-free ----
  const f32x4 pr0 = *(const f32x4*)&ldsP[(mp * 4 + 0) * 16 + kkq * 4];
  const f32x4 pr1 = *(const f32x4*)&ldsP[(mp * 4 + 1) * 16 + kkq * 4];
  const f32x4 pr2 = *(const f32x4*)&ldsP[(mp * 4 + 2) * 16 + kkq * 4];
  const f32x4 pr3 = *(const f32x4*)&ldsP[(mp * 4 + 3) * 16 + kkq * 4];
#define VCONS(i, slot, n) { \
    asm volatile("s_waitcnt vmcnt(" #n ")" ::: "memory"); \
    __builtin_amdgcn_sched_barrier(0); \
    const int c = w * 16 + (i); \
    const f32x4 vv = *(const f32x4*)(LDS + VRING + w * 3072 + (slot) * 1024 + lane * 16); \
    float p0 = pr0[0] * vv[0] + pr0[1] * vv[1] + pr0[2] * vv[2] + pr0[3] * vv[3]; \
    float p1 = pr1[0] * vv[0] + pr1[1] * vv[1] + pr1[2] * vv[2] + pr1[3] * vv[3]; \
    float p2 = pr2[0] * vv[0] + pr2[1] * vv[1] + pr2[2] * vv[2] + pr2[3] * vv[3]; \
    float p3 = pr3[0] * vv[0] + pr3[1] * vv[1] + pr3[2] * vv[2] + pr3[3] * vv[3]; \
    p0 += __shfl_xor(p0, 1); p0 += __shfl_xor(p0, 2); \
    p1 += __shfl_xor(p1, 1); p1 += __shfl_xor(p1, 2); \
    p2 += __shfl_xor(p2, 1); p2 += __shfl_xor(p2, 2); \
    p3 += __shfl_xor(p3, 1); p3 += __shfl_xor(p3, 2); \
    if (kkq == 0) { \
      uint2 o; \
      o.x = (uint32_t)f2bf(p0) | ((uint32_t)f2bf(p1) << 16); \
      o.y = (uint32_t)f2bf(p2) | ((uint32_t)f2bf(p3) << 16); \
      *(uint2*)(LDS + PVT + ((mp * 2048 + c * 8) ^ ((mp & 7) << 4))) = o; \
    } \
  }
  VCONS(0, 0, 2)  VISS(3, 0);
  VCONS(1, 1, 2)  VISS(4, 1);
  VCONS(2, 2, 2)  VISS(5, 2);
  VCONS(3, 0, 2)  VISS(6, 0);
  VCONS(4, 1, 2)  VISS(7, 1);
  VCONS(5, 2, 2)  VISS(8, 2);
  VCONS(6, 0, 2)  VISS(9, 0);
  VCONS(7, 1, 2)  VISS(10, 1);
  VCONS(8, 2, 2)  VISS(11, 2);
  VCONS(9, 0, 2)  VISS(12, 0);
  VCONS(10, 1, 2) VISS(13, 1);
  VCONS(11, 2, 2) VISS(14, 2);
  VCONS(12, 0, 2) VISS(15, 0);
  VCONS(13, 1, 2)
  VCONS(14, 2, 1)
  VCONS(15, 0, 0)
  asm volatile("s_waitcnt lgkmcnt(0)" ::: "memory");
  __builtin_amdgcn_s_barrier();          // pvt visible to all waves
  // ---- merge GEMM: out[o][m'] = Wmv(256x1024) x pvt(1024x16) + btot ----
  {
    const int wid = tid >> 6;            // A-row-block (rows wid*16..+15)
    const int bcol = lane & 15;          // m'
    const int kgrp = lane >> 4;          // 0..3
    f32x4 acc = {};
    for (int kgs = 0; kgs < 32; ++kgs) {
      const int byte = PVT + (((bcol * 2048 + kgs * 64 + kgrp * 16)) ^ ((bcol & 7) << 4));
      const short8 bb = *(const short8*)(LDS + byte);
      const short8 a0 = *(const short8*)(Wmv + (size_t)(((kgs * 16 + wid) * 64 + lane) * 8));
      acc = __builtin_amdgcn_mfma_f32_16x16x32_bf16(a0, bb, acc, 0, 0, 0);
    }
#pragma unroll
    for (int r = 0; r < 4; ++r) {
      const int o = wid * 16 + kgrp * 4 + r;
      out[((size_t)(b * DM_ + o)) * M_ + m0 + bcol] = acc[r] + btot[o];
    }
  }
  // ---- psum from prob LDS (moved to end so stores never perturb stream vmcnt) ----
  if (tid < 256) {
    const int mp2 = tid >> 4, kk = tid & 15;
    psum[((size_t)b * M_ + m0 + mp2) * KN_ + kk] =
        ldsP[(mp2 * 4 + 0) * 16 + kk] + ldsP[(mp2 * 4 + 1) * 16 + kk] +
        ldsP[(mp2 * 4 + 2) * 16 + kk] + ldsP[(mp2 * 4 + 3) * 16 + kk];
  }
#undef KISS
#undef VISS
#undef KCONS
#undef VCONS
}

extern "C" void kernel_launch(void* const* d_in, const int* in_sizes, int n_in,
                              void* d_out, int out_size, void* d_ws, size_t ws_size,
                              hipStream_t stream) {
  const float* query = (const float*)d_in[0];
  const float* key   = (const float*)d_in[1];
  const float* value = (const float*)d_in[2];
  const float* Wq = (const float*)d_in[3];
  const float* bq = (const float*)d_in[4];
  const float* Wk = (const float*)d_in[5];
  const float* bk = (const float*)d_in[6];  (void)bk;  // folded: softmax-invariant
  const float* Wv = (const float*)d_in[7];
  const float* bv = (const float*)d_in[8];
  const float* Wm = (const float*)d_in[9];
  const float* bm = (const float*)d_in[10];
  float* out  = (float*)d_out;
  float* psum = out + (size_t)B_ * DM_ * M_;   // outputs concatenated: out then prob_sum

  // ---- workspace layout (17.8 MB) ----
  const size_t Wmv_off  = 524288;
  const size_t qb2_off  = 1048576;
  const size_t btot_off = 1052672;
  const size_t qW_off   = 1053696;             // qW: 16.78 MB bf16

  unsigned short* W2T   = (unsigned short*)d_ws;
  unsigned short* Wmv   = (unsigned short*)((char*)d_ws + Wmv_off);
  float* qb2            = (float*)((char*)d_ws + qb2_off);
  float* btot           = (float*)((char*)d_ws + btot_off);
  unsigned short* qWbuf = (unsigned short*)((char*)d_ws + qW_off);

  prep2<<<dim3(1027), dim3(512), 0, stream>>>(Wq, bq, Wk, Wv, bv, Wm, bm, W2T, Wmv, qb2, btot);
  qw_gemm<<<dim3(B_ * 4 * 128), dim3(512), 0, stream>>>(query, W2T, qb2, qWbuf);
  fused_attn<<<dim3(512), dim3(1024), 0, stream>>>(key, value, qWbuf, Wmv, btot, out, psum);
}

// Round 15
// 96.170 us; speedup vs baseline: 1.1928x; 1.1358x over previous
//
#include <hip/hip_runtime.h>
#include <stdint.h>

#define DM_ 256
#define H_ 4
#define M_ 4096
#define KN_ 16
#define B_ 2
#define MK_ (M_*KN_)

typedef __attribute__((ext_vector_type(8))) short short8;
typedef __attribute__((ext_vector_type(4))) float f32x4;
typedef __attribute__((ext_vector_type(4))) unsigned short u16x4;

static __device__ __forceinline__ unsigned short f2bf(float x) {
  union { float f; uint32_t u; } v; v.f = x;
  uint32_t u = v.u + (0x7FFFu + ((v.u >> 16) & 1u));  // RNE
  return (unsigned short)(u >> 16);
}
static __device__ __forceinline__ float u2f(uint32_t u) {
  union { uint32_t u; float f; } v; v.u = u; return v.f;
}

// ---- prep2: weight products, fragment-linear bf16, fused biases ------------------------
__global__ void prep2(const float* __restrict__ Wq, const float* __restrict__ bq,
                      const float* __restrict__ Wk, const float* __restrict__ Wv,
                      const float* __restrict__ bv, const float* __restrict__ Wm,
                      const float* __restrict__ bm,
                      unsigned short* __restrict__ W2T, unsigned short* __restrict__ Wmv,
                      float* __restrict__ qb2, float* __restrict__ btot) {
  int t = blockIdx.x * 512 + threadIdx.x;
  if (t < 262144) {                       // W2T fragment-linear [kstep8][rowblk64][lane][8]
    int j = t & 7, lane = (t >> 3) & 63, rowblk = (t >> 9) & 63, kstep = t >> 15;
    int row = rowblk * 16 + (lane & 15);
    int k = kstep * 32 + (lane >> 4) * 8 + j;
    int h = row >> 8, c = row & 255;
    float v = 0.f;
#pragma unroll 8
    for (int d = 0; d < 64; ++d) v += Wq[(4 * d + h) * 256 + k] * Wk[(4 * d + h) * 256 + c];
    W2T[t] = f2bf(v);
  } else if (t < 524288) {                // Wmv fragment-linear [kstep32][rowblk16][lane][8]
    int e = t - 262144;
    int j = e & 7, lane = (e >> 3) & 63, rowblk = (e >> 9) & 15, kstep = e >> 13;
    int o = rowblk * 16 + (lane & 15);
    int kidx = kstep * 32 + (lane >> 4) * 8 + j;
    int c = kidx >> 2, h = kidx & 3;
    float v = 0.f;
#pragma unroll 8
    for (int d = 0; d < 64; ++d) v += Wm[o * 256 + 4 * d + h] * Wv[(4 * d + h) * 256 + c];
    Wmv[e] = f2bf(v);
  } else if (t < 525312) {
    int r = t - 524288; int h = r >> 8, c = r & 255;
    float v = 0.f;
#pragma unroll 8
    for (int d = 0; d < 64; ++d) v += bq[4 * d + h] * Wk[(4 * d + h) * 256 + c];
    qb2[r] = v;
  } else if (t < 525568) {
    int o = t - 525312;
    float v = bm[o];
#pragma unroll 8
    for (int c2 = 0; c2 < 256; ++c2) v += Wm[o * 256 + c2] * bv[c2];
    btot[o] = v;
  }
}

// ---- fused_attn: qw-GEMM + scores + softmax + PV + merge-GEMM + psum -------------------
// grid = B*256 = 512 blocks (XCD-chunked), 1024 threads (16 waves).
// KEY CHANGE vs R14: the qw_gemm kernel is FUSED into the head. Per block: stage the
// 16-m query slab (16 KB) into MFMA-B-fragment LDS layout, run the 1024x256x16 mini-GEMM
// (A = W2T fragment-linear, L2-resident 512 KB), add qb2, and scatter the accumulator
// directly into qsl's rotated layout. Eliminates the qW 33.6 MB HBM round-trip and one
// kernel launch. Streaming/softmax/PV/merge are verbatim R14 (barrier-free per-wave
// DMA rings, counted vmcnt, raw s_barriers at phase edges only).
// LDS plan (132 KB, phase-aliased):
//   [0,49152)        K-ring (wave w at w*3072)   -> scx f32[16][64][16] at [0,65536)
//   [49152,81920)    qsl 32 KB (score)           -> pvt 32 KB (PV/merge)
//   [81920,131072)   V-ring; head 12 KB doubles as QS (B-frags 8K) + QB (qb2 4K) at kernel start
//   [131072,135168)  prob f32[16][4][16]
__global__ __launch_bounds__(1024, 4)
void fused_attn(const float* __restrict__ key, const float* __restrict__ value,
                const float* __restrict__ query, const unsigned short* __restrict__ W2T,
                const float* __restrict__ qb2, const unsigned short* __restrict__ Wmv,
                const float* __restrict__ btot, float* __restrict__ out,
                float* __restrict__ psum) {
  __shared__ __align__(16) char LDS[135168];
  const int KRING = 0, QSL = 49152, SCX = 0, PVT = 49152, VRING = 81920;
  const int QS = 81920, QB = 90112, PROB = 131072;
  unsigned short* qsl = (unsigned short*)(LDS + QSL);
  float* ldsP = (float*)(LDS + PROB);
  const int tid = threadIdx.x;
  const int lane = tid & 63;
  const int w = tid >> 6;                                    // wave id 0..15
  const int vb = (blockIdx.x & 7) * 64 + (blockIdx.x >> 3);  // 512 = 8 XCD x 64
  const int b = vb >> 8;
  const int m0 = (vb & 255) * 16;
  // ---- stage query slab into B-frag layout + qb2 into LDS ----
  {
    const int cp = tid >> 2, q4 = (tid & 3) * 4;             // channel, m-quarter
    const float4 qv = *(const float4*)(query + (size_t)(b * DM_ + cp) * M_ + m0 + q4);
#pragma unroll
    for (int e = 0; e < 4; ++e) {
      const int mq2 = q4 + e;
      const int l = (((cp >> 3) & 3) << 4) | mq2;            // frag lane
      *(unsigned short*)(LDS + QS + ((cp >> 5) * 64 + l) * 16 + (cp & 7) * 2) =
          f2bf(((const float*)&qv)[e]);
    }
    ((float*)(LDS + QB))[tid] = qb2[tid];
  }
  __syncthreads();
  // ---- mini-GEMM: qsl[r=h*256+c][m'] = W2T x query_slab + qb2, scattered w/ rotation ----
  {
    f32x4 acc[4] = {};
#pragma unroll
    for (int kgs = 0; kgs < 8; ++kgs) {
      const short8 bb = *(const short8*)(LDS + QS + kgs * 1024 + lane * 16);
#pragma unroll
      for (int fi = 0; fi < 4; ++fi) {
        const short8 a0 = *(const short8*)(W2T + (size_t)(((kgs * 64 + w * 4 + fi) * 64 + lane) * 8));
        acc[fi] = __builtin_amdgcn_mfma_f32_16x16x32_bf16(a0, bb, acc[fi], 0, 0, 0);
      }
    }
    const int mq2 = lane & 15;
#pragma unroll
    for (int fi = 0; fi < 4; ++fi) {
#pragma unroll
      for (int rr = 0; rr < 4; ++rr) {
        const int r = (w * 4 + fi) * 16 + ((lane >> 4) << 2) + rr;
        const int h = r >> 8, c = r & 255;
        const int slot = (mq2 + c) & 15;
        qsl[c * 64 + slot * 4 + h] = f2bf(acc[fi][rr] + ((const float*)(LDS + QB))[r]);
      }
    }
  }
  __syncthreads();                       // qsl ready; all mini-GEMM loads retired (vmcnt 0)
  const int mp = lane >> 2;              // m-local 0..15
  const int kkq = lane & 3;              // kk quarter
  const float* ksrc = key   + (size_t)(b * 256) * 65536 + (size_t)m0 * 16 + lane * 4;
  const float* vsrc = value + (size_t)(b * 256) * 65536 + (size_t)m0 * 16 + lane * 4;
  f32x4 ps0 = {}, ps1 = {}, ps2 = {}, ps3 = {};

#define KISS(ch, slot) \
  __builtin_amdgcn_global_load_lds( \
      (const __attribute__((address_space(1))) uint32_t*)(ksrc + (size_t)(w * 16 + (ch)) * 65536), \
      (__attribute__((address_space(3))) uint32_t*)(LDS + KRING + w * 3072 + (slot) * 1024), 16, 0, 0)
#define VISS(ch, slot) \
  __builtin_amdgcn_global_load_lds( \
      (const __attribute__((address_space(1))) uint32_t*)(vsrc + (size_t)(w * 16 + (ch)) * 65536), \
      (__attribute__((address_space(3))) uint32_t*)(LDS + VRING + w * 3072 + (slot) * 1024), 16, 0, 0)
#define KCONS(i, slot, n) { \
    asm volatile("s_waitcnt vmcnt(" #n ")" ::: "memory"); \
    __builtin_amdgcn_sched_barrier(0); \
    const int c = w * 16 + (i); \
    const f32x4 kv = *(const f32x4*)(LDS + KRING + w * 3072 + (slot) * 1024 + lane * 16); \
    const uint2 qv = *(const uint2*)&qsl[c * 64 + (((mp + c) & 15)) * 4]; \
    ps0 += kv * u2f(qv.x << 16); \
    ps1 += kv * u2f(qv.x & 0xffff0000u); \
    ps2 += kv * u2f(qv.y << 16); \
    ps3 += kv * u2f(qv.y & 0xffff0000u); \
  }
  // ---- K stream: per-wave private ring, barrier-free ----
  KISS(0, 0); KISS(1, 1); KISS(2, 2);
  KCONS(0, 0, 2)  KISS(3, 0);
  KCONS(1, 1, 2)  KISS(4, 1);
  KCONS(2, 2, 2)  KISS(5, 2);
  KCONS(3, 0, 2)  KISS(6, 0);
  KCONS(4, 1, 2)  KISS(7, 1);
  KCONS(5, 2, 2)  KISS(8, 2);
  KCONS(6, 0, 2)  KISS(9, 0);
  KCONS(7, 1, 2)  KISS(10, 1);
  KCONS(8, 2, 2)  KISS(11, 2);
  KCONS(9, 0, 2)  KISS(12, 0);
  KCONS(10, 1, 2) KISS(13, 1);
  KCONS(11, 2, 2) KISS(14, 2);
  KCONS(12, 0, 2) KISS(15, 0);
  KCONS(13, 1, 2)
  KCONS(14, 2, 1)
  KCONS(15, 0, 0)
  // ---- V-ring prefill: 3 DMAs in flight across the softmax phase ----
  VISS(0, 0); VISS(1, 1); VISS(2, 2);
  __builtin_amdgcn_s_barrier();          // all waves left K loop (qsl/K-ring dead)
  // ---- scx write: [w][lane row][16 f32], slot-swizzled b128 stores ----
  {
    char* base = LDS + SCX + w * 4096 + lane * 64;
    const int sw = (lane >> 1) & 3;
    *(f32x4*)(base + ((0 ^ sw) << 4)) = ps0;
    *(f32x4*)(base + ((1 ^ sw) << 4)) = ps1;
    *(f32x4*)(base + ((2 ^ sw) << 4)) = ps2;
    *(f32x4*)(base + ((3 ^ sw) << 4)) = ps3;
  }
  asm volatile("s_waitcnt lgkmcnt(0)" ::: "memory");
  __builtin_amdgcn_s_barrier();
  // ---- reduce over 16 waves + softmax; thread t = m'(4b=wave)|h(2b)|kk(4b) ----
  {
    const int mp2 = tid >> 6;
    const int h2 = (lane >> 4) & 3;
    const int kk = lane & 15;
    const int lanep = mp2 * 4 + (kk >> 2);
    const int slotr = h2 ^ ((lanep >> 1) & 3);
    const int off = SCX + lanep * 64 + (slotr << 4) + (kk & 3) * 4;
    float sc = 0.f;
#pragma unroll
    for (int w2 = 0; w2 < 16; ++w2) sc += *(const float*)(LDS + w2 * 4096 + off);
    sc *= 0.125f;                        // 1/sqrt(64)
    float mx = sc;
    mx = fmaxf(mx, __shfl_xor(mx, 1)); mx = fmaxf(mx, __shfl_xor(mx, 2));
    mx = fmaxf(mx, __shfl_xor(mx, 4)); mx = fmaxf(mx, __shfl_xor(mx, 8));
    const float e = __expf(sc - mx);
    float sm = e;
    sm += __shfl_xor(sm, 1); sm += __shfl_xor(sm, 2);
    sm += __shfl_xor(sm, 4); sm += __shfl_xor(sm, 8);
    ldsP[(mp2 * 4 + h2) * 16 + kk] = e / sm;
  }
  asm volatile("s_waitcnt lgkmcnt(0)" ::: "memory");
  __builtin_amdgcn_s_barrier();
  // ---- V stream + PV: per-wave private ring, barrier-free ----
  const f32x4 pr0 = *(const f32x4*)&ldsP[(mp * 4 + 0) * 16 + kkq * 4];
  const f32x4 pr1 = *(const f32x4*)&ldsP[(mp * 4 + 1) * 16 + kkq * 4];
  const f32x4 pr2 = *(const f32x4*)&ldsP[(mp * 4 + 2) * 16 + kkq * 4];
  const f32x4 pr3 = *(const f32x4*)&ldsP[(mp * 4 + 3) * 16 + kkq * 4];
#define VCONS(i, slot, n) { \
    asm volatile("s_waitcnt vmcnt(" #n ")" ::: "memory"); \
    __builtin_amdgcn_sched_barrier(0); \
    const int c = w * 16 + (i); \
    const f32x4 vv = *(const f32x4*)(LDS + VRING + w * 3072 + (slot) * 1024 + lane * 16); \
    float p0 = pr0[0] * vv[0] + pr0[1] * vv[1] + pr0[2] * vv[2] + pr0[3] * vv[3]; \
    float p1 = pr1[0] * vv[0] + pr1[1] * vv[1] + pr1[2] * vv[2] + pr1[3] * vv[3]; \
    float p2 = pr2[0] * vv[0] + pr2[1] * vv[1] + pr2[2] * vv[2] + pr2[3] * vv[3]; \
    float p3 = pr3[0] * vv[0] + pr3[1] * vv[1] + pr3[2] * vv[2] + pr3[3] * vv[3]; \
    p0 += __shfl_xor(p0, 1); p0 += __shfl_xor(p0, 2); \
    p1 += __shfl_xor(p1, 1); p1 += __shfl_xor(p1, 2); \
    p2 += __shfl_xor(p2, 1); p2 += __shfl_xor(p2, 2); \
    p3 += __shfl_xor(p3, 1); p3 += __shfl_xor(p3, 2); \
    if (kkq == 0) { \
      uint2 o; \
      o.x = (uint32_t)f2bf(p0) | ((uint32_t)f2bf(p1) << 16); \
      o.y = (uint32_t)f2bf(p2) | ((uint32_t)f2bf(p3) << 16); \
      *(uint2*)(LDS + PVT + ((mp * 2048 + c * 8) ^ ((mp & 7) << 4))) = o; \
    } \
  }
  VCONS(0, 0, 2)  VISS(3, 0);
  VCONS(1, 1, 2)  VISS(4, 1);
  VCONS(2, 2, 2)  VISS(5, 2);
  VCONS(3, 0, 2)  VISS(6, 0);
  VCONS(4, 1, 2)  VISS(7, 1);
  VCONS(5, 2, 2)  VISS(8, 2);
  VCONS(6, 0, 2)  VISS(9, 0);
  VCONS(7, 1, 2)  VISS(10, 1);
  VCONS(8, 2, 2)  VISS(11, 2);
  VCONS(9, 0, 2)  VISS(12, 0);
  VCONS(10, 1, 2) VISS(13, 1);
  VCONS(11, 2, 2) VISS(14, 2);
  VCONS(12, 0, 2) VISS(15, 0);
  VCONS(13, 1, 2)
  VCONS(14, 2, 1)
  VCONS(15, 0, 0)
  asm volatile("s_waitcnt lgkmcnt(0)" ::: "memory");
  __builtin_amdgcn_s_barrier();          // pvt visible to all waves
  // ---- merge GEMM: out[o][m'] = Wmv(256x1024) x pvt(1024x16) + btot ----
  {
    const int wid = tid >> 6;            // A-row-block (rows wid*16..+15)
    const int bcol = lane & 15;          // m'
    const int kgrp = lane >> 4;          // 0..3
    f32x4 acc = {};
    for (int kgs = 0; kgs < 32; ++kgs) {
      const int byte = PVT + (((bcol * 2048 + kgs * 64 + kgrp * 16)) ^ ((bcol & 7) << 4));
      const short8 bb = *(const short8*)(LDS + byte);
      const short8 a0 = *(const short8*)(Wmv + (size_t)(((kgs * 16 + wid) * 64 + lane) * 8));
      acc = __builtin_amdgcn_mfma_f32_16x16x32_bf16(a0, bb, acc, 0, 0, 0);
    }
#pragma unroll
    for (int r = 0; r < 4; ++r) {
      const int o = wid * 16 + kgrp * 4 + r;
      out[((size_t)(b * DM_ + o)) * M_ + m0 + bcol] = acc[r] + btot[o];
    }
  }
  // ---- psum from prob LDS ----
  if (tid < 256) {
    const int mp2 = tid >> 4, kk = tid & 15;
    psum[((size_t)b * M_ + m0 + mp2) * KN_ + kk] =
        ldsP[(mp2 * 4 + 0) * 16 + kk] + ldsP[(mp2 * 4 + 1) * 16 + kk] +
        ldsP[(mp2 * 4 + 2) * 16 + kk] + ldsP[(mp2 * 4 + 3) * 16 + kk];
  }
#undef KISS
#undef VISS
#undef KCONS
#undef VCONS
}

extern "C" void kernel_launch(void* const* d_in, const int* in_sizes, int n_in,
                              void* d_out, int out_size, void* d_ws, size_t ws_size,
                              hipStream_t stream) {
  const float* query = (const float*)d_in[0];
  const float* key   = (const float*)d_in[1];
  const float* value = (const float*)d_in[2];
  const float* Wq = (const float*)d_in[3];
  const float* bq = (const float*)d_in[4];
  const float* Wk = (const float*)d_in[5];
  const float* bk = (const float*)d_in[6];  (void)bk;  // folded: softmax-invariant
  const float* Wv = (const float*)d_in[7];
  const float* bv = (const float*)d_in[8];
  const float* Wm = (const float*)d_in[9];
  const float* bm = (const float*)d_in[10];
  float* out  = (float*)d_out;
  float* psum = out + (size_t)B_ * DM_ * M_;   // outputs concatenated: out then prob_sum

  // ---- workspace layout (1.05 MB: weight products + fused biases only) ----
  const size_t Wmv_off  = 524288;
  const size_t qb2_off  = 1048576;
  const size_t btot_off = 1052672;

  unsigned short* W2T   = (unsigned short*)d_ws;
  unsigned short* Wmv   = (unsigned short*)((char*)d_ws + Wmv_off);
  float* qb2            = (float*)((char*)d_ws + qb2_off);
  float* btot           = (float*)((char*)d_ws + btot_off);

  prep2<<<dim3(1027), dim3(512), 0, stream>>>(Wq, bq, Wk, Wv, bv, Wm, bm, W2T, Wmv, qb2, btot);
  fused_attn<<<dim3(512), dim3(1024), 0, stream>>>(key, value, query, W2T, qb2,
                                                   Wmv, btot, out, psum);
}